// Round 13
// baseline (527.871 us; speedup 1.0000x reference)
//
#include <hip/hip_runtime.h>

// OSNAP sketch: out[n,f] = sum_d x[n,d] * P[f,d]
// x: [16384,4096] f32. P: [8192,4096] f32, exactly 4 nonzeros (+-0.5) per COLUMN.
// v13 = v10 components (row-major padded LDS, global_load_lds staging, 4x
// ds_read_b32 per entry, d-sorted sums) restructured: 8 rows/block staged into
// TWO buffers up-front, ONE __syncthreads total, ent4 hoisted to registers and
// reused for both 4-row groups (halves ent4 L2 traffic), f32x4 stores.
// No mid-loop barriers -> stores never drained (round-6/round-12 lesson).

#define D_IN    4096
#define D_FEAT  8192
#define N_TOT   16384
#define CAP     16        // per-row clamp (P(Poisson(2) >= 16) ~ 4e-10 per row)
#define NR      4         // x-rows per group
#define PADW    8         // pad words per LDS row (zero slot for dummy entries)
#define ROWW    (D_IN + PADW)     // 4104 words
#define BUFW    (NR * ROWW)       // 16416 words = 65,664 B per buffer
#define OVF_CAP 16384

typedef float f32x4 __attribute__((ext_vector_type(4)));

// ---------------- ws layout (bytes, NO overlaps) ----------------
// 0        row_cnt  int  [D_FEAT]      32768
// 32768    row_ent  int2 [D_FEAT*CAP]  1048576 -> 1081344  (.x=d, .y=bits(val))
// 1081344  ent4     int4 [D_FEAT]      131072  -> 1212416  (4 packed entries/row)
// 1212416  ovf_desc int  [D_FEAT]      32768   -> 1245184  ((start<<5)|extra)
// 1245184  ovf_ents int  [OVF_CAP]     65536   -> 1310720
// 1310720  ovf_base int  [1]           4

// Full-BW streaming scan of P (128MB), binning nonzeros directly into row lists.
__global__ void k_scan(const f32x4* __restrict__ p4,
                       int* __restrict__ row_cnt, int2* __restrict__ row_ent,
                       int* __restrict__ ovf_base) {
    if (blockIdx.x == 0 && threadIdx.x == 0) ovf_base[0] = 0;  // used by next kernel
    const long total = (long)D_FEAT * D_IN / 4;
    for (long q = (long)blockIdx.x * blockDim.x + threadIdx.x; q < total;
         q += (long)gridDim.x * blockDim.x) {
        f32x4 v = __builtin_nontemporal_load(&p4[q]);
        long base = q * 4;
        float vals[4] = {v.x, v.y, v.z, v.w};
        #pragma unroll
        for (int c = 0; c < 4; ++c) {
            if (vals[c] != 0.0f) {
                long i = base + c;
                int f = (int)(i >> 12);          // / D_IN
                int d = (int)(i & (D_IN - 1));   // % D_IN
                int slot = atomicAdd(&row_cnt[f], 1);
                if (slot < CAP) row_ent[f * CAP + slot] = make_int2(d, __float_as_int(vals[c]));
            }
        }
    }
}

// Per row f: sort entries by d (distinct -> deterministic), pack first 4 into
// int4 (entry = d*4 | sign<<31; dummy = D_IN*4 -> zeroed pad word; bit30 of .w =
// overflow flag), extras -> atomically-allocated compact slab. Slab offsets vary
// run-to-run but per-row entry ORDER doesn't -> bitwise-deterministic output.
__global__ void k_sortpack(const int* __restrict__ row_cnt, int2* __restrict__ row_ent,
                           int4* __restrict__ ent4, int* __restrict__ ovf_desc,
                           int* __restrict__ ovf_ents, int* __restrict__ ovf_base) {
    int f = blockIdx.x * blockDim.x + threadIdx.x;
    if (f >= D_FEAT) return;
    int cnt = row_cnt[f];
    if (cnt > CAP) cnt = CAP;
    for (int a = 1; a < cnt; ++a) {
        int2 key = row_ent[f * CAP + a];
        int b = a - 1;
        while (b >= 0) {
            int2 cur = row_ent[f * CAP + b];
            if (cur.x <= key.x) break;
            row_ent[f * CAP + b + 1] = cur;
            --b;
        }
        row_ent[f * CAP + b + 1] = key;
    }
    int e[4];
    #pragma unroll
    for (int j = 0; j < 4; ++j) {
        if (j < cnt) {
            int2 ev = row_ent[f * CAP + j];
            e[j] = (ev.x * 4) | (int)((unsigned)ev.y & 0x80000000u);
        } else {
            e[j] = D_IN * 4;   // dummy -> zeroed pad word
        }
    }
    int extra = (cnt > 4) ? (cnt - 4) : 0;
    int start = 0;
    if (extra) {
        start = atomicAdd(ovf_base, extra);
        if (start < 0) start = 0;
        if (start > OVF_CAP - CAP) start = OVF_CAP - CAP;   // capacity guard
        for (int j = 0; j < extra; ++j) {
            int2 ev = row_ent[f * CAP + 4 + j];
            ovf_ents[start + j] = (ev.x * 4) | (int)((unsigned)ev.y & 0x80000000u);
        }
        e[3] |= 0x40000000;
    }
    ovf_desc[f] = (start << 5) | extra;
    ent4[f] = make_int4(e[0], e[1], e[2], e[3]);
}

// Direct global->LDS 16B async copy (no VGPR round-trip). LDS dest is
// wave-uniform base + lane*16; global src is per-lane.
__device__ __forceinline__ void load_lds16(const float* g, float* l) {
    __builtin_amdgcn_global_load_lds(
        (const __attribute__((address_space(1))) void*)g,
        (__attribute__((address_space(3))) void*)l, 16, 0, 0);
}

// Main gather: 8 rows/block in 2 buffers, single barrier, 1 block/CU.
__global__ __launch_bounds__(1024, 4) void k_gather(const float* __restrict__ x,
                                                    const int4* __restrict__ ent4,
                                                    const int* __restrict__ ovf_desc,
                                                    const int* __restrict__ ovf_ents,
                                                    float* __restrict__ out) {
    __shared__ float xs[2 * BUFW];   // 131,328 B -> 1 block/CU
    const int tid = threadIdx.x;
    const int wav = tid >> 6;
    const int n0 = blockIdx.x * (2 * NR);
    const int f0 = tid * 8;          // this thread's 8 features (both groups)

    // Stage rows n0..n0+3 -> buf0, n0+4..n0+7 -> buf1 (8x gload_lds/thread).
    {
        const float* gb = x + (size_t)n0 * D_IN + (tid << 2);
        float* lb = xs + wav * 256;
        #pragma unroll
        for (int r = 0; r < NR; ++r) {
            load_lds16(gb + r * D_IN,            lb + r * ROWW);
            load_lds16(gb + (NR + r) * D_IN,     lb + BUFW + r * ROWW);
        }
    }
    // Hoist structure: 8 int4/thread, reused for both groups.
    const int4 e0 = ent4[f0 + 0], e1 = ent4[f0 + 1], e2 = ent4[f0 + 2], e3 = ent4[f0 + 3];
    const int4 e4 = ent4[f0 + 4], e5 = ent4[f0 + 5], e6 = ent4[f0 + 6], e7 = ent4[f0 + 7];
    // Zero pad words of BOTH buffers (dummy entries read word D_IN of each row).
    if (tid < 2 * NR * PADW) {
        int b = tid >> 5, r = (tid >> 3) & 3, w = tid & 7;
        xs[b * BUFW + r * ROWW + D_IN + w] = 0.f;
    }
    __syncthreads();   // the ONLY barrier: stages + ent4 landed

    // ENT adds one packed entry (byte-off | sign<<31) to one feature's 4 accs.
    #define ENT(EE, A0, A1, A2, A3) { \
        int off_ = (EE) & 0x7FFC; \
        float v0_ = *(const float*)(xb  + off_); \
        float v1_ = *(const float*)(xb  + off_ + ROWW * 4); \
        float v2_ = *(const float*)(xb2 + off_); \
        float v3_ = *(const float*)(xb2 + off_ + ROWW * 4); \
        unsigned sg_ = (unsigned)(EE) & 0x80000000u; \
        A0 += __uint_as_float(__float_as_uint(v0_) ^ sg_); \
        A1 += __uint_as_float(__float_as_uint(v1_) ^ sg_); \
        A2 += __uint_as_float(__float_as_uint(v2_) ^ sg_); \
        A3 += __uint_as_float(__float_as_uint(v3_) ^ sg_); }

    // QUAD: 4 features (quads Q0..Q3) at base FB -> one f32x4 NT store per row.
    #define QUAD(Q0, Q1, Q2, Q3, FB) { \
        float a00=0,a01=0,a02=0,a03=0, a10=0,a11=0,a12=0,a13=0; \
        float a20=0,a21=0,a22=0,a23=0, a30=0,a31=0,a32=0,a33=0; \
        ENT(Q0.x,a00,a01,a02,a03) ENT(Q0.y,a00,a01,a02,a03) \
        ENT(Q0.z,a00,a01,a02,a03) ENT(Q0.w,a00,a01,a02,a03) \
        ENT(Q1.x,a10,a11,a12,a13) ENT(Q1.y,a10,a11,a12,a13) \
        ENT(Q1.z,a10,a11,a12,a13) ENT(Q1.w,a10,a11,a12,a13) \
        ENT(Q2.x,a20,a21,a22,a23) ENT(Q2.y,a20,a21,a22,a23) \
        ENT(Q2.z,a20,a21,a22,a23) ENT(Q2.w,a20,a21,a22,a23) \
        ENT(Q3.x,a30,a31,a32,a33) ENT(Q3.y,a30,a31,a32,a33) \
        ENT(Q3.z,a30,a31,a32,a33) ENT(Q3.w,a30,a31,a32,a33) \
        if ((Q0.w | Q1.w | Q2.w | Q3.w) & 0x40000000) {   /* rare tails */ \
            if (Q0.w & 0x40000000) { int od = ovf_desc[(FB)+0]; int ex = od & 31; \
                const int* oe = ovf_ents + (od >> 5); \
                for (int j = 0; j < ex; ++j) { int ee = oe[j]; ENT(ee,a00,a01,a02,a03) } } \
            if (Q1.w & 0x40000000) { int od = ovf_desc[(FB)+1]; int ex = od & 31; \
                const int* oe = ovf_ents + (od >> 5); \
                for (int j = 0; j < ex; ++j) { int ee = oe[j]; ENT(ee,a10,a11,a12,a13) } } \
            if (Q2.w & 0x40000000) { int od = ovf_desc[(FB)+2]; int ex = od & 31; \
                const int* oe = ovf_ents + (od >> 5); \
                for (int j = 0; j < ex; ++j) { int ee = oe[j]; ENT(ee,a20,a21,a22,a23) } } \
            if (Q3.w & 0x40000000) { int od = ovf_desc[(FB)+3]; int ex = od & 31; \
                const int* oe = ovf_ents + (od >> 5); \
                for (int j = 0; j < ex; ++j) { int ee = oe[j]; ENT(ee,a30,a31,a32,a33) } } \
        } \
        f32x4 r0_ = {a00*0.5f, a10*0.5f, a20*0.5f, a30*0.5f}; \
        f32x4 r1_ = {a01*0.5f, a11*0.5f, a21*0.5f, a31*0.5f}; \
        f32x4 r2_ = {a02*0.5f, a12*0.5f, a22*0.5f, a32*0.5f}; \
        f32x4 r3_ = {a03*0.5f, a13*0.5f, a23*0.5f, a33*0.5f}; \
        __builtin_nontemporal_store(r0_, (f32x4*)(og + 0 * D_FEAT + (FB))); \
        __builtin_nontemporal_store(r1_, (f32x4*)(og + 1 * D_FEAT + (FB))); \
        __builtin_nontemporal_store(r2_, (f32x4*)(og + 2 * D_FEAT + (FB))); \
        __builtin_nontemporal_store(r3_, (f32x4*)(og + 3 * D_FEAT + (FB))); }

    // Group 0 (buf0, rows n0..n0+3).
    {
        const char* xb  = (const char*)xs;
        const char* xb2 = xb + 2 * (ROWW * 4);
        float* og = out + (size_t)n0 * D_FEAT;
        QUAD(e0, e1, e2, e3, f0)
        QUAD(e4, e5, e6, e7, f0 + 4)
    }
    // Group 1 (buf1, rows n0+4..n0+7): no barrier needed, buf1 staged up-front;
    // group-0 stores stream underneath this compute.
    {
        const char* xb  = (const char*)xs + BUFW * 4;
        const char* xb2 = xb + 2 * (ROWW * 4);
        float* og = out + (size_t)(n0 + NR) * D_FEAT;
        QUAD(e0, e1, e2, e3, f0)
        QUAD(e4, e5, e6, e7, f0 + 4)
    }
    #undef QUAD
    #undef ENT
}

extern "C" void kernel_launch(void* const* d_in, const int* in_sizes, int n_in,
                              void* d_out, int out_size, void* d_ws, size_t ws_size,
                              hipStream_t stream) {
    const float* x = (const float*)d_in[0];
    const float* P = (const float*)d_in[1];
    float* out = (float*)d_out;

    char* ws = (char*)d_ws;
    int*   row_cnt  = (int*)  (ws + 0);
    int2*  row_ent  = (int2*) (ws + 32768);
    int4*  ent4     = (int4*) (ws + 1081344);
    int*   ovf_desc = (int*)  (ws + 1212416);
    int*   ovf_ents = (int*)  (ws + 1245184);
    int*   ovf_base = (int*)  (ws + 1310720);

    hipMemsetAsync(row_cnt, 0, 32768, stream);
    k_scan    <<<2048, 256, 0, stream>>>((const f32x4*)P, row_cnt, row_ent, ovf_base);
    k_sortpack<<<(D_FEAT + 255) / 256, 256, 0, stream>>>(row_cnt, row_ent, ent4,
                                                         ovf_desc, ovf_ents, ovf_base);
    k_gather  <<<N_TOT / (2 * NR), 1024, 0, stream>>>(x, ent4, ovf_desc, ovf_ents, out);
}

// Round 14
// 183.329 us; speedup vs baseline: 2.8794x; 2.8794x over previous
//
#include <hip/hip_runtime.h>

// OSNAP sketch: out[n,f] = sum_d x[n,d] * P[f,d]
// x: [16384,4096] f32. P: [8192,4096] f32, exactly 4 nonzeros (+-0.5) per COLUMN.
// v14 = v10 restored (best measured: 186.1 us). NR=4, 1024 thr, row-major
// padded LDS, global_load_lds staging, single barrier, 4 phases x 2 features
// (VGPR<=64 -> 2 blocks/CU), dense f32x2 NT stores. Only delta vs v10:
// ovf_base zeroing folded into k_scan (one fewer dispatch).
// Locked-in lessons: no 131KB/1-block configs (v6/v12/v13 ~300-530 us), no
// reg-staging (+11 us, v9/v11), no NR=2 (v8), no counted vmcnt (compiler
// inserts its own vmcnt(0), v12), stores must be lane-dense (v12/v13).

#define D_IN    4096
#define D_FEAT  8192
#define N_TOT   16384
#define CAP     16        // per-row clamp (P(Poisson(2) >= 16) ~ 4e-10 per row)
#define NR      4         // x-rows per gather block
#define PH      2048      // feature stride per phase (1024 threads * 2)
#define PADW    8         // pad words per LDS row (zero slot for dummy entries)
#define ROWW    (D_IN + PADW)       // 4104 words
#define OVF_CAP 16384

typedef float f32x4 __attribute__((ext_vector_type(4)));
typedef float f32x2 __attribute__((ext_vector_type(2)));

// ---------------- ws layout (bytes, NO overlaps) ----------------
// 0        row_cnt  int  [D_FEAT]      32768
// 32768    row_ent  int2 [D_FEAT*CAP]  1048576 -> 1081344  (.x=d, .y=bits(val))
// 1081344  ent4     int4 [D_FEAT]      131072  -> 1212416  (4 packed entries/row)
// 1212416  ovf_desc int  [D_FEAT]      32768   -> 1245184  ((start<<5)|extra)
// 1245184  ovf_ents int  [OVF_CAP]     65536   -> 1310720
// 1310720  ovf_base int  [1]           4

// Full-BW streaming scan of P (128MB), binning nonzeros directly into row lists.
__global__ void k_scan(const f32x4* __restrict__ p4,
                       int* __restrict__ row_cnt, int2* __restrict__ row_ent,
                       int* __restrict__ ovf_base) {
    if (blockIdx.x == 0 && threadIdx.x == 0) ovf_base[0] = 0;  // for k_sortpack
    const long total = (long)D_FEAT * D_IN / 4;
    for (long q = (long)blockIdx.x * blockDim.x + threadIdx.x; q < total;
         q += (long)gridDim.x * blockDim.x) {
        f32x4 v = __builtin_nontemporal_load(&p4[q]);
        long base = q * 4;
        float vals[4] = {v.x, v.y, v.z, v.w};
        #pragma unroll
        for (int c = 0; c < 4; ++c) {
            if (vals[c] != 0.0f) {
                long i = base + c;
                int f = (int)(i >> 12);          // / D_IN
                int d = (int)(i & (D_IN - 1));   // % D_IN
                int slot = atomicAdd(&row_cnt[f], 1);
                if (slot < CAP) row_ent[f * CAP + slot] = make_int2(d, __float_as_int(vals[c]));
            }
        }
    }
}

// Per row f: sort entries by d (distinct -> deterministic), pack first 4 into
// int4 (entry = d*4 | sign<<31; dummy = D_IN*4 -> zeroed pad word; bit30 of .w =
// overflow flag), extras -> atomically-allocated compact slab. Slab offsets vary
// run-to-run but per-row entry ORDER doesn't -> bitwise-deterministic output.
__global__ void k_sortpack(const int* __restrict__ row_cnt, int2* __restrict__ row_ent,
                           int4* __restrict__ ent4, int* __restrict__ ovf_desc,
                           int* __restrict__ ovf_ents, int* __restrict__ ovf_base) {
    int f = blockIdx.x * blockDim.x + threadIdx.x;
    if (f >= D_FEAT) return;
    int cnt = row_cnt[f];
    if (cnt > CAP) cnt = CAP;
    for (int a = 1; a < cnt; ++a) {
        int2 key = row_ent[f * CAP + a];
        int b = a - 1;
        while (b >= 0) {
            int2 cur = row_ent[f * CAP + b];
            if (cur.x <= key.x) break;
            row_ent[f * CAP + b + 1] = cur;
            --b;
        }
        row_ent[f * CAP + b + 1] = key;
    }
    int e[4];
    #pragma unroll
    for (int j = 0; j < 4; ++j) {
        if (j < cnt) {
            int2 ev = row_ent[f * CAP + j];
            e[j] = (ev.x * 4) | (int)((unsigned)ev.y & 0x80000000u);
        } else {
            e[j] = D_IN * 4;   // dummy -> zeroed pad word
        }
    }
    int extra = (cnt > 4) ? (cnt - 4) : 0;
    int start = 0;
    if (extra) {
        start = atomicAdd(ovf_base, extra);
        if (start < 0) start = 0;
        if (start > OVF_CAP - CAP) start = OVF_CAP - CAP;   // capacity guard
        for (int j = 0; j < extra; ++j) {
            int2 ev = row_ent[f * CAP + 4 + j];
            ovf_ents[start + j] = (ev.x * 4) | (int)((unsigned)ev.y & 0x80000000u);
        }
        e[3] |= 0x40000000;
    }
    ovf_desc[f] = (start << 5) | extra;
    ent4[f] = make_int4(e[0], e[1], e[2], e[3]);
}

// Direct global->LDS 16B async copy (no VGPR round-trip). LDS dest is
// wave-uniform base + lane*16; global src is per-lane.
__device__ __forceinline__ void load_lds16(const float* g, float* l) {
    __builtin_amdgcn_global_load_lds(
        (const __attribute__((address_space(1))) void*)g,
        (__attribute__((address_space(3))) void*)l, 16, 0, 0);
}

// Main gather: one 4-row group per block, single barrier, 2 blocks/CU.
__global__ __launch_bounds__(1024, 8) __attribute__((amdgpu_waves_per_eu(8)))
void k_gather(const float* __restrict__ x,
              const int4* __restrict__ ent4,
              const int* __restrict__ ovf_desc,
              const int* __restrict__ ovf_ents,
              float* __restrict__ out) {
    __shared__ float xs[NR * ROWW];   // 65,664 B
    const int n0 = blockIdx.x * NR;
    const int tid = threadIdx.x;
    const int wav = tid >> 6;
    const int fb = tid * 2;

    // Prefetch phase-0 structure quads: they land under the staging loads.
    int4 qa0 = ent4[fb + 0];
    int4 qa1 = ent4[fb + 1];

    // Stage rows n0..n0+3 row-major via global_load_lds(16B): per wave the LDS
    // dest is uniform base + lane*16 -> linear; global src fully coalesced.
    {
        const float* gb = x + (size_t)n0 * D_IN + tid * 4;
        float* lb = xs + wav * 256;
        load_lds16(gb,             lb);
        load_lds16(gb + D_IN,      lb + ROWW);
        load_lds16(gb + 2 * D_IN,  lb + 2 * ROWW);
        load_lds16(gb + 3 * D_IN,  lb + 3 * ROWW);
    }
    // zero the pad words (dummy entries read word D_IN of each row)
    if (tid < NR * PADW) xs[(tid >> 3) * ROWW + D_IN + (tid & 7)] = 0.f;
    __syncthreads();   // implicit vmcnt(0): staging + prefetched quads landed

    const char* xsb  = (const char*)xs;                 // rows 0,1
    const char* xsb2 = (const char*)(xs + 2 * ROWW);    // rows 2,3 (imm range)
    float* o0 = out + (size_t)n0 * D_FEAT;
    float* o1 = o0 + D_FEAT;
    float* o2 = o1 + D_FEAT;
    float* o3 = o2 + D_FEAT;

    // ENT adds one packed entry (byte-off | sign<<31) to one feature's 4 accs.
    #define ENT(EE, A0, A1, A2, A3) { \
        int off_ = (EE) & 0x7FFC; \
        float v0_ = *(const float*)(xsb  + off_); \
        float v1_ = *(const float*)(xsb  + off_ + ROWW * 4); \
        float v2_ = *(const float*)(xsb2 + off_); \
        float v3_ = *(const float*)(xsb2 + off_ + ROWW * 4); \
        unsigned sg_ = (unsigned)(EE) & 0x80000000u; \
        A0 += __uint_as_float(__float_as_uint(v0_) ^ sg_); \
        A1 += __uint_as_float(__float_as_uint(v1_) ^ sg_); \
        A2 += __uint_as_float(__float_as_uint(v2_) ^ sg_); \
        A3 += __uint_as_float(__float_as_uint(v3_) ^ sg_); }

    // PHASE computes 2 features (quads Q0,Q1) at base FB; dense f32x2 stores.
    #define PHASE(Q0, Q1, FB) { \
        float a00=0,a01=0,a02=0,a03=0, a10=0,a11=0,a12=0,a13=0; \
        ENT(Q0.x,a00,a01,a02,a03) ENT(Q0.y,a00,a01,a02,a03) \
        ENT(Q0.z,a00,a01,a02,a03) ENT(Q0.w,a00,a01,a02,a03) \
        ENT(Q1.x,a10,a11,a12,a13) ENT(Q1.y,a10,a11,a12,a13) \
        ENT(Q1.z,a10,a11,a12,a13) ENT(Q1.w,a10,a11,a12,a13) \
        if ((Q0.w | Q1.w) & 0x40000000) {   /* rare overflow tails */ \
            if (Q0.w & 0x40000000) { int od = ovf_desc[(FB)+0]; int ex = od & 31; \
                const int* oe = ovf_ents + (od >> 5); \
                for (int j = 0; j < ex; ++j) { int ee = oe[j]; ENT(ee,a00,a01,a02,a03) } } \
            if (Q1.w & 0x40000000) { int od = ovf_desc[(FB)+1]; int ex = od & 31; \
                const int* oe = ovf_ents + (od >> 5); \
                for (int j = 0; j < ex; ++j) { int ee = oe[j]; ENT(ee,a10,a11,a12,a13) } } \
        } \
        f32x2 s0_ = {a00*0.5f, a10*0.5f}; \
        f32x2 s1_ = {a01*0.5f, a11*0.5f}; \
        f32x2 s2_ = {a02*0.5f, a12*0.5f}; \
        f32x2 s3_ = {a03*0.5f, a13*0.5f}; \
        __builtin_nontemporal_store(s0_, (f32x2*)(o0 + (FB))); \
        __builtin_nontemporal_store(s1_, (f32x2*)(o1 + (FB))); \
        __builtin_nontemporal_store(s2_, (f32x2*)(o2 + (FB))); \
        __builtin_nontemporal_store(s3_, (f32x2*)(o3 + (FB))); }

    // 4 phases; next phase's quads load while current phase computes.
    int4 qb0 = ent4[fb + PH + 0];
    int4 qb1 = ent4[fb + PH + 1];
    PHASE(qa0, qa1, fb)

    qa0 = ent4[fb + 2 * PH + 0];
    qa1 = ent4[fb + 2 * PH + 1];
    PHASE(qb0, qb1, fb + PH)

    qb0 = ent4[fb + 3 * PH + 0];
    qb1 = ent4[fb + 3 * PH + 1];
    PHASE(qa0, qa1, fb + 2 * PH)

    PHASE(qb0, qb1, fb + 3 * PH)

    #undef PHASE
    #undef ENT
}

extern "C" void kernel_launch(void* const* d_in, const int* in_sizes, int n_in,
                              void* d_out, int out_size, void* d_ws, size_t ws_size,
                              hipStream_t stream) {
    const float* x = (const float*)d_in[0];
    const float* P = (const float*)d_in[1];
    float* out = (float*)d_out;

    char* ws = (char*)d_ws;
    int*   row_cnt  = (int*)  (ws + 0);
    int2*  row_ent  = (int2*) (ws + 32768);
    int4*  ent4     = (int4*) (ws + 1081344);
    int*   ovf_desc = (int*)  (ws + 1212416);
    int*   ovf_ents = (int*)  (ws + 1245184);
    int*   ovf_base = (int*)  (ws + 1310720);

    hipMemsetAsync(row_cnt, 0, 32768, stream);
    k_scan    <<<2048, 256, 0, stream>>>((const f32x4*)P, row_cnt, row_ent, ovf_base);
    k_sortpack<<<(D_FEAT + 255) / 256, 256, 0, stream>>>(row_cnt, row_ent, ent4,
                                                         ovf_desc, ovf_ents, ovf_base);
    k_gather  <<<N_TOT / NR, 1024, 0, stream>>>(x, ent4, ovf_desc, ovf_ents, out);
}